// Round 2
// 564.365 us; speedup vs baseline: 1.1777x; 1.1777x over previous
//
#include <hip/hip_runtime.h>
#include <hip/hip_bf16.h>

// Problem constants
#define BATCH   65536
#define D       1024      // INPUT_DIM
#define L       100       // LATENT_DIM
#define C       21        // NUM_EMBEDDINGS
#define NPAD    112       // L padded to multiple of 16 for MFMA

typedef __bf16 bf16x8 __attribute__((ext_vector_type(8)));
typedef float  f32x4  __attribute__((ext_vector_type(4)));

// ---------------- workspace layout (bytes) ----------------
// [0, 8192)        double bsums[1024]   per-block loss partials (k_main -> k_final)
// [8192, 270336)   float  p[65536]      UNUSED (kept for layout stability)
// [270336, 356352) float  u[21][1024]   W_enc^T @ codebook^T  (c-major)
// [356352, 356480) float  t[32]         ||c||^2 - 2 b_enc.c
// [356480, 442496) float  R[21][1024]   codebook @ W_dec^T + b_dec
// [442496, 671872) bf16   Wb[112][1024] W_enc in bf16, zero-padded rows
static constexpr size_t OFF_P  = 8192;
static constexpr size_t OFF_U  = OFF_P + (size_t)BATCH * 4;
static constexpr size_t OFF_T  = OFF_U + (size_t)C * D * 4;
static constexpr size_t OFF_R  = OFF_T + 128;
static constexpr size_t OFF_WB = OFF_R + (size_t)C * D * 4;

// ---------------- kernel 1: setup (tiny) ----------------
__global__ __launch_bounds__(256) void k_setup(
    const float* __restrict__ W_enc, const float* __restrict__ b_enc,
    const float* __restrict__ cb,    const float* __restrict__ W_dec,
    const float* __restrict__ b_dec,
    float* __restrict__ u, float* __restrict__ t, float* __restrict__ R,
    __bf16* __restrict__ Wb)
{
    int id = blockIdx.x * 256 + threadIdx.x;
    if (id < C * D) {                       // u[c][k] = sum_j cb[c][j] * W_enc[j][k]
        int c = id >> 10, k = id & 1023;
        float s = 0.f;
        for (int j = 0; j < L; j++) s += cb[c * L + j] * W_enc[j * D + k];
        u[id] = s;
    } else if (id < 2 * C * D) {            // R[c][k] = sum_j cb[c][j] * W_dec[k][j] + b_dec[k]
        int i2 = id - C * D;
        int c = i2 >> 10, k = i2 & 1023;
        float s = 0.f;
        for (int j = 0; j < L; j++) s += cb[c * L + j] * W_dec[k * L + j];
        R[i2] = s + b_dec[k];
    } else if (id < 2 * C * D + NPAD * D) { // Wb[n][k] bf16 (zero pad n>=100)
        int i3 = id - 2 * C * D;
        int n = i3 >> 10, k = i3 & 1023;
        Wb[i3] = (n < L) ? (__bf16)W_enc[n * D + k] : (__bf16)0.f;
    } else if (id < 2 * C * D + NPAD * D + C) { // t[c]
        int c = id - 2 * C * D - NPAD * D;
        float s = 0.f, b2 = 0.f;
        for (int j = 0; j < L; j++) {
            float cv = cb[c * L + j];
            s  += cv * cv;
            b2 += b_enc[j] * cv;
        }
        t[c] = s - 2.f * b2;
    }
}

// ---------------- kernel 2: FUSED scores + argmin + recon + ||z_e||^2 loss ----------------
// 64 rows/block, 4 waves. K is processed in 64-float chunks so x is read from
// HBM exactly once: the f32 score phase (argmin precision-critical) warms L1,
// the bf16 MFMA phase re-reads the same 16KB chunk from L1/L2.
//   score phase: wave w covers cols [k0+w*16, k0+w*16+16) of all 64 rows;
//                u addresses are wave-uniform -> scalar s_load broadcast.
//   mfma  phase: wave w owns rows [w*16, w*16+16); lane (n15,q) reads
//                x[w*16+n15][k0+ks*32+q*8..+8], 7 n-tiles of Wb.
__global__ __launch_bounds__(256) void k_main(
    const float* __restrict__ x, const float* __restrict__ u,
    const float* __restrict__ t, const float* __restrict__ R,
    const __bf16* __restrict__ Wb, const float* __restrict__ b_enc,
    float* __restrict__ outR, float* __restrict__ outIdx,
    double* __restrict__ bsums)
{
    __shared__ float part[4][64][22];   // score partials, pad 22 (2-way bank ok)
    __shared__ float pbest[64];
    __shared__ int   idxs[64];
    __shared__ float bpart[16];

    const int lane = threadIdx.x & 63;
    const int wave = __builtin_amdgcn_readfirstlane(threadIdx.x >> 6); // force SGPR
    const int row0 = blockIdx.x * 64;
    const int n15  = lane & 15;
    const int q    = lane >> 4;

    float sacc[C];
#pragma unroll
    for (int c = 0; c < C; c++) sacc[c] = 0.f;
    f32x4 zacc[7];
#pragma unroll
    for (int nt = 0; nt < 7; nt++) zacc[nt] = (f32x4){0.f, 0.f, 0.f, 0.f};

    // score: this lane's row, this wave's 16-col slice of each chunk
    const float* xs = x + (size_t)(row0 + lane) * D + wave * 16;
    const float* ub = u + wave * 16;                    // wave-uniform base
    // mfma: A fragment row for this lane
    const float* xm = x + (size_t)(row0 + wave * 16 + n15) * D + q * 8;

    for (int k0 = 0; k0 < D; k0 += 64) {
        // ---- score quarter: 16 floats, f32, u via scalar broadcast ----
#pragma unroll
        for (int j2 = 0; j2 < 4; j2++) {
            float4 xv = *(const float4*)(xs + k0 + j2 * 4);
#pragma unroll
            for (int c = 0; c < C; c++) {
                const float* uc = ub + c * D + k0 + j2 * 4;  // uniform -> s_load
                sacc[c] += xv.x * uc[0] + xv.y * uc[1] + xv.z * uc[2] + xv.w * uc[3];
            }
        }
        // ---- mfma: 2 k-steps of 32, x re-read from L1-hot chunk ----
#pragma unroll
        for (int ks = 0; ks < 2; ks++) {
            float4 a0 = *(const float4*)(xm + k0 + ks * 32);
            float4 a1 = *(const float4*)(xm + k0 + ks * 32 + 4);
            bf16x8 af;
            af[0] = (__bf16)a0.x; af[1] = (__bf16)a0.y; af[2] = (__bf16)a0.z; af[3] = (__bf16)a0.w;
            af[4] = (__bf16)a1.x; af[5] = (__bf16)a1.y; af[6] = (__bf16)a1.z; af[7] = (__bf16)a1.w;
#pragma unroll
            for (int nt = 0; nt < 7; nt++) {
                bf16x8 bfr = *(const bf16x8*)(Wb + (size_t)(nt * 16 + n15) * D + k0 + ks * 32 + q * 8);
                zacc[nt] = __builtin_amdgcn_mfma_f32_16x16x32_bf16(af, bfr, zacc[nt], 0, 0, 0);
            }
        }
        // keep waves in lockstep for L1 chunk locality (no memory deps -> raw barrier)
        __builtin_amdgcn_s_barrier();
    }

    // ---- cross-wave score reduce + argmin (wave 0) ----
#pragma unroll
    for (int c = 0; c < C; c++) part[wave][lane][c] = sacc[c];
    __syncthreads();
    if (wave == 0) {
        float best = 3.0e38f;
        int   bi   = 0;
#pragma unroll
        for (int c = 0; c < C; c++) {
            float s = part[0][lane][c] + part[1][lane][c]
                    + part[2][lane][c] + part[3][lane][c];
            float score = t[c] - 2.0f * s;
            if (score < best) { best = score; bi = c; }   // first-min on ties
        }
        idxs[lane]         = bi;
        pbest[lane]        = best;          // == t_idx - 2 s_idx (loss row term)
        outIdx[row0 + lane] = (float)bi;
    }
    __syncthreads();

    // ---- ||z_e||^2 + p : same math/order as the old k_loss ----
    // zacc layout: col = n15 + 16*nt, row (within wave tile) = q*4 + r
    float rn[4] = {0.f, 0.f, 0.f, 0.f};
#pragma unroll
    for (int nt = 0; nt < 7; nt++) {
        int col = nt * 16 + n15;
        float bn = (col < L) ? b_enc[col] : 0.f;
#pragma unroll
        for (int r = 0; r < 4; r++) {
            float z = zacc[nt][r] + bn;     // pad cols: MFMA gives 0, bn=0 -> 0
            rn[r] += z * z;
        }
    }
#pragma unroll
    for (int off = 1; off < 16; off <<= 1) {
#pragma unroll
        for (int r = 0; r < 4; r++) rn[r] += __shfl_xor(rn[r], off, 64);
    }
    if (n15 == 0) {
        float s4 = 0.f;
#pragma unroll
        for (int r = 0; r < 4; r++) s4 += rn[r] + pbest[wave * 16 + q * 4 + r];
        bpart[wave * 4 + q] = s4;
    }
    __syncthreads();
    if (threadIdx.x == 0) {
        double bs = 0.0;
        for (int i = 0; i < 16; i++) bs += (double)bpart[i];
        bsums[blockIdx.x] = bs;
    }

    // ---- x_recon rows = R[idx]: 256 threads x 16B = one 4KB row per iter ----
    // non-temporal stores: outR is never re-read, keep L2 for x/R/Wb.
    // f32x4 (clang ext_vector) rather than HIP float4: nontemporal builtin
    // requires a scalar/vector-of-scalar pointee.
    for (int r = 0; r < 64; r++) {
        int id = idxs[r];
        const f32x4 v = ((const f32x4*)(R + (size_t)id * D))[threadIdx.x];
        __builtin_nontemporal_store(v, ((f32x4*)(outR + (size_t)(row0 + r) * D)) + threadIdx.x);
    }
}

// ---------------- kernel 3: finalize loss ----------------
__global__ __launch_bounds__(256) void k_final(
    const double* __restrict__ bsums, float* __restrict__ out_loss)
{
    __shared__ double wsum[4];
    int t = threadIdx.x;
    double s = bsums[t] + bsums[t + 256] + bsums[t + 512] + bsums[t + 768];
    for (int off = 32; off; off >>= 1) s += __shfl_down(s, off, 64);
    if ((t & 63) == 0) wsum[t >> 6] = s;
    __syncthreads();
    if (t == 0) {
        double tot = wsum[0] + wsum[1] + wsum[2] + wsum[3];
        out_loss[0] = (float)(1.1 * tot / ((double)BATCH * (double)L));
    }
}

// ---------------- launch ----------------
extern "C" void kernel_launch(void* const* d_in, const int* in_sizes, int n_in,
                              void* d_out, int out_size, void* d_ws, size_t ws_size,
                              hipStream_t stream) {
    const float* x     = (const float*)d_in[0];
    const float* W_enc = (const float*)d_in[1];
    const float* b_enc = (const float*)d_in[2];
    const float* cb    = (const float*)d_in[3];
    const float* W_dec = (const float*)d_in[4];
    const float* b_dec = (const float*)d_in[5];

    char*   ws    = (char*)d_ws;
    double* bsums = (double*)ws;
    float*  u     = (float*)(ws + OFF_U);
    float*  t     = (float*)(ws + OFF_T);
    float*  R     = (float*)(ws + OFF_R);
    __bf16* Wb    = (__bf16*)(ws + OFF_WB);

    float* outR    = (float*)d_out;                       // 65536*1024
    float* outLoss = outR + (size_t)BATCH * D;            // 1
    float* outIdx  = outLoss + 1;                         // 65536 (as float values)

    k_setup<<<617, 256, 0, stream>>>(W_enc, b_enc, cb, W_dec, b_dec, u, t, R, Wb);
    k_main <<<BATCH / 64, 256, 0, stream>>>(x, u, t, R, Wb, b_enc, outR, outIdx, bsums);
    k_final<<<1, 256, 0, stream>>>(bsums, outLoss);
}